// Round 4
// baseline (64.873 us; speedup 1.0000x reference)
//
#include <hip/hip_runtime.h>
#include <math.h>

#define ALPHA 0.001f
#define GAMMA 0.01f
#define DD 784
#define TD 1568          // 2*D floats per template row
#define XF2 392          // f2 per x row
#define NF2 784          // valid f2 per coded row
#define PF2 832          // padded f2 per coded row (13*64)
#define NCHUNK 13
#define MM 256
#define BB 1024
#define NCLS 10
#define ROWS_PB 8

// ws layout (floats):
//   [0..255]    per-block partial min of x
//   [256..511]  per-block partial max of x
//   [512..767]  scale[m] = committed ? 1/denom : -1

__global__ __launch_bounds__(256) void k_minmax(const float* __restrict__ x,
                                                float* __restrict__ ws,
                                                int* __restrict__ out_bits) {
  const float4* x4 = (const float4*)x;
  const int n4 = BB * DD / 4;  // 200704
  int tid = blockIdx.x * 256 + threadIdx.x;

  // init output to -inf bits (poison is not re-applied between replays)
  if (tid < BB * NCLS) out_bits[tid] = 0xFF800000;

  float mn = 1e30f, mx = -1e30f;
  for (int i = tid; i < n4; i += 256 * 256) {
    float4 v = x4[i];
    mn = fminf(mn, fminf(fminf(v.x, v.y), fminf(v.z, v.w)));
    mx = fmaxf(mx, fmaxf(fmaxf(v.x, v.y), fmaxf(v.z, v.w)));
  }
#pragma unroll
  for (int off = 32; off; off >>= 1) {
    mn = fminf(mn, __shfl_xor(mn, off, 64));
    mx = fmaxf(mx, __shfl_xor(mx, off, 64));
  }
  __shared__ float smn[4], smx[4];
  int lane = threadIdx.x & 63, wid = threadIdx.x >> 6;
  if (lane == 0) { smn[wid] = mn; smx[wid] = mx; }
  __syncthreads();
  if (threadIdx.x == 0) {
    mn = fminf(fminf(smn[0], smn[1]), fminf(smn[2], smn[3]));
    mx = fmaxf(fmaxf(smx[0], smx[1]), fmaxf(smx[2], smx[3]));
    ws[blockIdx.x] = mn;
    ws[256 + blockIdx.x] = mx;
  }
}

__global__ __launch_bounds__(64) void k_denom(const float* __restrict__ T,
                                              const int* __restrict__ committed,
                                              const int* __restrict__ counts,
                                              float* __restrict__ scale_out) {
  int m = blockIdx.x;
  int lane = threadIdx.x;
  const float4* t4 = (const float4*)(T + m * TD);
  float s = 0.f;
  for (int i = lane; i < TD / 4; i += 64) {
    float4 v = t4[i];
    s += (v.x + v.y) + (v.z + v.w);
  }
#pragma unroll
  for (int off = 32; off; off >>= 1) s += __shfl_xor(s, off, 64);
  if (lane == 0) {
    float denom = ALPHA + s + GAMMA * (float)counts[m];
    scale_out[m] = committed[m] ? (1.0f / denom) : -1.0f;
  }
}

// grid: 2048 blocks = 128 rowgroups x 16 tgroups (bid = rg*16 + tg).
// 512 threads = 8 waves; wave w owns templates {tg*16 + 2w, tg*16 + 2w + 1}
// held fully in registers (13 float2 chunks/lane, interleaved stride-64).
// Block stages 8 complement-coded rows in LDS.
__global__ __launch_bounds__(512) void k_main(const float* __restrict__ x,
                                              const float* __restrict__ T,
                                              const int* __restrict__ labels,
                                              const float* __restrict__ ws,
                                              int* __restrict__ out_bits) {
  __shared__ float2 coded[ROWS_PB * PF2];   // 8*832*8 = 53248 B
  __shared__ int clsmax[ROWS_PB][NCLS];
  __shared__ float wred[16];
  __shared__ float s_stats[2];

  int tid = threadIdx.x;
  int lane = tid & 63, wid = tid >> 6;
  int rg = blockIdx.x >> 4;
  int tg = blockIdx.x & 15;
  int row0 = rg * ROWS_PB;
  int m0 = tg * 16 + wid * 2;

  // ---- phase 0: finish global min/max reduction from 256 partials ----
  float mn = (tid < 256) ? ws[tid] : 1e30f;
  float mx = (tid < 256) ? ws[256 + tid] : -1e30f;
#pragma unroll
  for (int off = 32; off; off >>= 1) {
    mn = fminf(mn, __shfl_xor(mn, off, 64));
    mx = fmaxf(mx, __shfl_xor(mx, off, 64));
  }
  if (lane == 0) { wred[wid] = mn; wred[8 + wid] = mx; }
  if (tid < ROWS_PB * NCLS) clsmax[tid / NCLS][tid % NCLS] = 0xFF800000;
  __syncthreads();
  if (tid == 0) {
    mn = wred[0]; mx = wred[8];
#pragma unroll
    for (int w = 1; w < 8; ++w) { mn = fminf(mn, wred[w]); mx = fmaxf(mx, wred[8 + w]); }
    s_stats[0] = mn;
    s_stats[1] = 1.0f / (mx - mn + 1e-10f);
  }

  // ---- template prologue (no LDS dependency; overlaps phase-0 latency) ----
  const float2* t0 = (const float2*)(T + (size_t)m0 * TD);
  const float2* t1 = (const float2*)(T + (size_t)(m0 + 1) * TD);
  float2 tA[NCHUNK], tB[NCHUNK];
#pragma unroll
  for (int k = 0; k < NCHUNK; ++k) {
    int idx = k * 64 + lane;
    if (idx > NF2 - 1) idx = NF2 - 1;   // clamp tail (k=12, lane>=16); coded pad=0 -> min()=0
    tA[k] = t0[idx];
    tB[k] = t1[idx];
  }
  float scA = ws[512 + m0], scB = ws[512 + m0 + 1];
  int lblA = labels[m0], lblB = labels[m0 + 1];

  __syncthreads();
  float fmn = s_stats[0], finv = s_stats[1];

  // ---- phase 1: stage 8 normalized complement-coded rows into LDS ----
  for (int idx = tid; idx < ROWS_PB * PF2; idx += 512) {
    int r = idx / PF2;
    int p = idx - r * PF2;
    const float2* xr = (const float2*)(x + (size_t)(row0 + r) * DD);
    float2 v;
    if (p < XF2) {
      float2 t = xr[p];
      v.x = (t.x - fmn) * finv;  v.y = (t.y - fmn) * finv;
    } else if (p < NF2) {
      float2 t = xr[p - XF2];
      v.x = 1.f - (t.x - fmn) * finv;  v.y = 1.f - (t.y - fmn) * finv;
    } else {
      v.x = 0.f; v.y = 0.f;
    }
    coded[idx] = v;
  }
  __syncthreads();

  // ---- phase 2: fuzzy-AND over 8 rows, templates stationary in regs ----
  for (int r = 0; r < ROWS_PB; ++r) {
    const float2* crow = coded + r * PF2;
    float aAx = 0.f, aAy = 0.f, aBx = 0.f, aBy = 0.f;
#pragma unroll
    for (int k = 0; k < NCHUNK; ++k) {
      float2 cv = crow[k * 64 + lane];
      aAx += fminf(cv.x, tA[k].x);  aAy += fminf(cv.y, tA[k].y);
      aBx += fminf(cv.x, tB[k].x);  aBy += fminf(cv.y, tB[k].y);
    }
    float sA = aAx + aAy, sB = aBx + aBy;
    sA += __shfl_xor(sA, 32, 64);
    sB += __shfl_xor(sB, 32, 64);
    float c = (lane < 32) ? sA : sB;   // lanes<32 reduce A, lanes>=32 reduce B
#pragma unroll
    for (int off = 16; off; off >>= 1) c += __shfl_xor(c, off, 64);
    if ((lane & 31) == 0) {
      float sc = (lane == 0) ? scA : scB;
      int lb   = (lane == 0) ? lblA : lblB;
      if (sc > 0.f) atomicMax(&clsmax[r][lb], __float_as_int(c * sc));
    }
  }
  __syncthreads();

  // ---- epilogue: combine across the 16 tgroup blocks ----
  if (tid < ROWS_PB * NCLS) {
    int rr = tid / NCLS, cc = tid - rr * NCLS;
    int bits = clsmax[rr][cc];
    if (bits != 0xFF800000)
      atomicMax(&out_bits[(row0 + rr) * NCLS + cc], bits);
  }
}

extern "C" void kernel_launch(void* const* d_in, const int* in_sizes, int n_in,
                              void* d_out, int out_size, void* d_ws, size_t ws_size,
                              hipStream_t stream) {
  const float* x = (const float*)d_in[0];
  const float* T = (const float*)d_in[1];
  const int* committed = (const int*)d_in[2];
  const int* labels = (const int*)d_in[3];
  const int* counts = (const int*)d_in[4];
  int* out_bits = (int*)d_out;
  float* ws = (float*)d_ws;

  k_minmax<<<dim3(256), dim3(256), 0, stream>>>(x, ws, out_bits);
  k_denom<<<dim3(256), dim3(64), 0, stream>>>(T, committed, counts, ws + 512);
  k_main<<<dim3(2048), dim3(512), 0, stream>>>(x, T, labels, ws, out_bits);
}

// Round 5
// 58.527 us; speedup vs baseline: 1.1084x; 1.1084x over previous
//
#include <hip/hip_runtime.h>
#include <math.h>

#define ALPHA 0.001f
#define GAMMA 0.01f
#define DD 784
#define TD 1568          // 2*D floats per template row
#define XF2 392          // f2 per x row
#define NF2 784          // valid f2 per coded row
#define PF2 832          // padded f2 per coded row (13*64)
#define NCHUNK 13
#define MM 256
#define BB 1024
#define NCLS 10
#define ROWS_PB 8
#define TG 16

// ws layout (floats):
//   [0..255]    per-block partial min of x
//   [256..511]  per-block partial max of x
//   [512..767]  scale[m] = committed ? 1/denom : -1
//   [768]       final min
//   [769]       1/(max-min+1e-10)

__global__ __launch_bounds__(256) void k_minmax(const float* __restrict__ x,
                                                float* __restrict__ ws,
                                                int* __restrict__ out_bits) {
  const float4* x4 = (const float4*)x;
  const int n4 = BB * DD / 4;  // 200704
  int tid = blockIdx.x * 256 + threadIdx.x;

  // init output to -inf bits (poison is not re-applied between replays)
  if (tid < BB * NCLS) out_bits[tid] = 0xFF800000;

  float mn = 1e30f, mx = -1e30f;
  for (int i = tid; i < n4; i += 256 * 256) {
    float4 v = x4[i];
    mn = fminf(mn, fminf(fminf(v.x, v.y), fminf(v.z, v.w)));
    mx = fmaxf(mx, fmaxf(fmaxf(v.x, v.y), fmaxf(v.z, v.w)));
  }
#pragma unroll
  for (int off = 32; off; off >>= 1) {
    mn = fminf(mn, __shfl_xor(mn, off, 64));
    mx = fmaxf(mx, __shfl_xor(mx, off, 64));
  }
  __shared__ float smn[4], smx[4];
  int lane = threadIdx.x & 63, wid = threadIdx.x >> 6;
  if (lane == 0) { smn[wid] = mn; smx[wid] = mx; }
  __syncthreads();
  if (threadIdx.x == 0) {
    mn = fminf(fminf(smn[0], smn[1]), fminf(smn[2], smn[3]));
    mx = fmaxf(fmaxf(smx[0], smx[1]), fmaxf(smx[2], smx[3]));
    ws[blockIdx.x] = mn;
    ws[256 + blockIdx.x] = mx;
  }
}

__global__ __launch_bounds__(256) void k_stats(float* __restrict__ ws) {
  int tid = threadIdx.x;
  float mn = ws[tid], mx = ws[256 + tid];
#pragma unroll
  for (int off = 32; off; off >>= 1) {
    mn = fminf(mn, __shfl_xor(mn, off, 64));
    mx = fmaxf(mx, __shfl_xor(mx, off, 64));
  }
  __shared__ float smn[4], smx[4];
  int lane = tid & 63, wid = tid >> 6;
  if (lane == 0) { smn[wid] = mn; smx[wid] = mx; }
  __syncthreads();
  if (tid == 0) {
    mn = fminf(fminf(smn[0], smn[1]), fminf(smn[2], smn[3]));
    mx = fmaxf(fmaxf(smx[0], smx[1]), fmaxf(smx[2], smx[3]));
    ws[768] = mn;
    ws[769] = 1.0f / (mx - mn + 1e-10f);
  }
}

__global__ __launch_bounds__(64) void k_denom(const float* __restrict__ T,
                                              const int* __restrict__ committed,
                                              const int* __restrict__ counts,
                                              float* __restrict__ scale_out) {
  int m = blockIdx.x;
  int lane = threadIdx.x;
  const float4* t4 = (const float4*)(T + m * TD);
  float s = 0.f;
  for (int i = lane; i < TD / 4; i += 64) {
    float4 v = t4[i];
    s += (v.x + v.y) + (v.z + v.w);
  }
#pragma unroll
  for (int off = 32; off; off >>= 1) s += __shfl_xor(s, off, 64);
  if (lane == 0) {
    float denom = ALPHA + s + GAMMA * (float)counts[m];
    scale_out[m] = committed[m] ? (1.0f / denom) : -1.0f;
  }
}

// grid: 2048 blocks = 128 rowgroups x 16 tgroups (bid = rg*16 + tg).
// 512 threads = 8 waves; wave w owns templates {tg*16 + 2w, tg*16 + 2w + 1}.
// Phase 2 is chunk-outer/row-inner: per k, 2 coalesced template loads (used
// immediately -> no resident template array, no spill) + 8 LDS row reads into
// 16 accumulators. Reductions deferred to one bulk butterfly pass.
__global__ __launch_bounds__(512) void k_main(const float* __restrict__ x,
                                              const float* __restrict__ T,
                                              const int* __restrict__ labels,
                                              const float* __restrict__ ws,
                                              int* __restrict__ out_bits) {
  __shared__ float2 coded[ROWS_PB * PF2];   // 53248 B
  __shared__ int clsmax[ROWS_PB][NCLS];

  int tid = threadIdx.x;
  int lane = tid & 63, wid = tid >> 6;
  int rg = blockIdx.x >> 4;
  int tg = blockIdx.x & 15;
  int row0 = rg * ROWS_PB;
  int m0 = tg * 16 + wid * 2;

  float fmn = ws[768], finv = ws[769];          // uniform scalar loads
  float scA = ws[512 + m0], scB = ws[512 + m0 + 1];
  int lblA = labels[m0], lblB = labels[m0 + 1];

  if (tid < ROWS_PB * NCLS) clsmax[tid / NCLS][tid % NCLS] = 0xFF800000;

  // ---- phase 1: stage 8 normalized complement-coded rows into LDS ----
  for (int idx = tid; idx < ROWS_PB * PF2; idx += 512) {
    int r = idx / PF2;
    int p = idx - r * PF2;
    const float2* xr = (const float2*)(x + (size_t)(row0 + r) * DD);
    float2 v;
    if (p < XF2) {
      float2 t = xr[p];
      v.x = (t.x - fmn) * finv;  v.y = (t.y - fmn) * finv;
    } else if (p < NF2) {
      float2 t = xr[p - XF2];
      v.x = 1.f - (t.x - fmn) * finv;  v.y = 1.f - (t.y - fmn) * finv;
    } else {
      v.x = 0.f; v.y = 0.f;
    }
    coded[idx] = v;
  }
  __syncthreads();

  // ---- phase 2: chunk-outer fuzzy-AND, 16 accumulators ----
  float accA[ROWS_PB], accB[ROWS_PB];
#pragma unroll
  for (int r = 0; r < ROWS_PB; ++r) { accA[r] = 0.f; accB[r] = 0.f; }

  const float2* tp0 = (const float2*)(T + (size_t)m0 * TD);
  const float2* tp1 = (const float2*)(T + (size_t)(m0 + 1) * TD);

#pragma unroll 2
  for (int k = 0; k < NCHUNK; ++k) {
    int idx = k * 64 + lane;
    int tidx = (idx > NF2 - 1) ? (NF2 - 1) : idx;  // clamp template tail; coded pad=0 -> min()=0
    float2 tA = tp0[tidx];
    float2 tB = tp1[tidx];
#pragma unroll
    for (int r = 0; r < ROWS_PB; ++r) {
      float2 cv = coded[r * PF2 + idx];
      accA[r] += fminf(cv.x, tA.x) + fminf(cv.y, tA.y);
      accB[r] += fminf(cv.x, tB.x) + fminf(cv.y, tB.y);
    }
  }

  // ---- bulk reduce: 16 independent 64-lane butterflies (pipelined) ----
#pragma unroll
  for (int r = 0; r < ROWS_PB; ++r) {
#pragma unroll
    for (int off = 32; off; off >>= 1) {
      accA[r] += __shfl_xor(accA[r], off, 64);
      accB[r] += __shfl_xor(accB[r], off, 64);
    }
  }
  // lane r<8 -> template A row r; lane 8..15 -> template B row lane-8
  float vout = 0.f;
#pragma unroll
  for (int r = 0; r < ROWS_PB; ++r) {
    if (lane == r)     vout = accA[r];
    if (lane == 8 + r) vout = accB[r];
  }
  if (lane < 16) {
    float sc = (lane < 8) ? scA : scB;
    int lb   = (lane < 8) ? lblA : lblB;
    if (sc > 0.f) atomicMax(&clsmax[lane & 7][lb], __float_as_int(vout * sc));
  }
  __syncthreads();

  // ---- epilogue: combine across the 16 tgroup blocks ----
  if (tid < ROWS_PB * NCLS) {
    int rr = tid / NCLS, cc = tid - rr * NCLS;
    int bits = clsmax[rr][cc];
    if (bits != 0xFF800000)
      atomicMax(&out_bits[(row0 + rr) * NCLS + cc], bits);
  }
}

extern "C" void kernel_launch(void* const* d_in, const int* in_sizes, int n_in,
                              void* d_out, int out_size, void* d_ws, size_t ws_size,
                              hipStream_t stream) {
  const float* x = (const float*)d_in[0];
  const float* T = (const float*)d_in[1];
  const int* committed = (const int*)d_in[2];
  const int* labels = (const int*)d_in[3];
  const int* counts = (const int*)d_in[4];
  int* out_bits = (int*)d_out;
  float* ws = (float*)d_ws;

  k_minmax<<<dim3(256), dim3(256), 0, stream>>>(x, ws, out_bits);
  k_stats<<<dim3(1), dim3(256), 0, stream>>>(ws);
  k_denom<<<dim3(256), dim3(64), 0, stream>>>(T, committed, counts, ws + 512);
  k_main<<<dim3(2048), dim3(512), 0, stream>>>(x, T, labels, ws, out_bits);
}